// Round 5
// baseline (563.579 us; speedup 1.0000x reference)
//
#include <hip/hip_runtime.h>
#include <hip/hip_bf16.h>
#include <math.h>

// Problem: CausalSelfAttention  B=4 T=2048 D=1024 H=16 HD=64
// d_in: fp32 x[4,2048,1024], Wq,Wk,Wv,Wp[1024,1024], bp[1024]; d_out: fp32 y.
// Pipeline: cvt(fp32->bf16 into ws) -> qkv -> attn -> proj.
// V is stored TRANSPOSED [B,H,HD,T] (produced by operand-swapped MFMA in qkv)
// so attention's PV A-operand fragments are contiguous b128 loads.

#define B_  4
#define T_  2048
#define D_  1024
#define H_  16
#define HD_ 64
#define M_  (B_ * T_)   // 8192 rows

typedef short bf16x8 __attribute__((ext_vector_type(8)));
typedef float f32x4  __attribute__((ext_vector_type(4)));

__device__ __forceinline__ f32x4 mfma16(bf16x8 a, bf16x8 b, f32x4 c) {
    return __builtin_amdgcn_mfma_f32_16x16x32_bf16(a, b, c, 0, 0, 0);
}

__device__ __forceinline__ void gl_lds16(const unsigned short* g, unsigned short* l) {
    __builtin_amdgcn_global_load_lds(
        (const __attribute__((address_space(1))) void*)g,
        (__attribute__((address_space(3))) void*)l, 16, 0, 0);
}

__device__ __forceinline__ unsigned short f2bf(float f) {
    union { __hip_bfloat16 h; unsigned short u; } cv;
    cv.h = __float2bfloat16(f);
    return cv.u;
}
__device__ __forceinline__ float bf2f(unsigned short u) {
    return __uint_as_float(((unsigned)u) << 16);
}
__device__ __forceinline__ float exp2_fast(float x) {
    return __builtin_amdgcn_exp2f(x);   // v_exp_f32: 2^x
}

struct su4 { unsigned short x, y, z, w; };

// ---------------------------------------------------------------------------
__global__ __launch_bounds__(256)
void cvt_kernel(const float* __restrict__ in, unsigned short* __restrict__ out) {
    const int i = blockIdx.x * 256 + threadIdx.x;
    const float4 v = ((const float4*)in)[i];
    su4 o;
    o.x = f2bf(v.x); o.y = f2bf(v.y); o.z = f2bf(v.z); o.w = f2bf(v.w);
    ((su4*)out)[i] = o;
}

// ---------------------------------------------------------------------------
// Fused QKV GEMM: C = X @ W^T.  Q,K scattered to [B,H,T,HD]; V to [B,H,HD,T]
// via operand-swapped MFMA (acc holds C^T for the V section).
// ---------------------------------------------------------------------------
__global__ __launch_bounds__(256, 2)
void qkv_kernel(const unsigned short* __restrict__ X,
                const unsigned short* __restrict__ Wq,
                const unsigned short* __restrict__ Wk,
                const unsigned short* __restrict__ Wv,
                unsigned short* __restrict__ Qo,
                unsigned short* __restrict__ Ko,
                unsigned short* __restrict__ Vo)
{
    __shared__ unsigned short As[128 * 64];
    __shared__ unsigned short Bs[128 * 64];

    const int m0 = blockIdx.x * 128;
    const int by = blockIdx.y;
    const unsigned short* W = (by < 8) ? Wq : (by < 16) ? Wk : Wv;
    unsigned short*       O = (by < 8) ? Qo : (by < 16) ? Ko : Vo;
    const int n0   = (by & 7) * 128;
    const bool vsec = (by >= 16);
    const int tid  = threadIdx.x;
    const int lane = tid & 63;
    const int wv   = tid >> 6;
    const int wr   = (wv >> 1) * 64;
    const int wc   = (wv & 1) * 64;
    const int g    = lane >> 4;
    const int c    = lane & 15;

    f32x4 acc[4][4] = {};

    for (int k0 = 0; k0 < D_; k0 += 64) {
        #pragma unroll
        for (int i = 0; i < 4; ++i) {
            const int flat = i * 2048 + tid * 8;
            const int row = flat >> 6, col = flat & 63;
            gl_lds16(X + (size_t)(m0 + row) * D_ + k0 + col, As + flat);
            gl_lds16(W + (size_t)(n0 + row) * D_ + k0 + col, Bs + flat);
        }
        __syncthreads();
        #pragma unroll
        for (int kk = 0; kk < 64; kk += 32) {
            bf16x8 af[4], bg[4];
            #pragma unroll
            for (int mi = 0; mi < 4; ++mi)
                af[mi] = *(const bf16x8*)(As + (wr + mi * 16 + c) * 64 + kk + g * 8);
            #pragma unroll
            for (int ni = 0; ni < 4; ++ni)
                bg[ni] = *(const bf16x8*)(Bs + (wc + ni * 16 + c) * 64 + kk + g * 8);
            if (!vsec) {
                #pragma unroll
                for (int mi = 0; mi < 4; ++mi)
                    #pragma unroll
                    for (int ni = 0; ni < 4; ++ni)
                        acc[mi][ni] = mfma16(af[mi], bg[ni], acc[mi][ni]);
            } else {
                #pragma unroll
                for (int mi = 0; mi < 4; ++mi)
                    #pragma unroll
                    for (int ni = 0; ni < 4; ++ni)
                        acc[mi][ni] = mfma16(bg[ni], af[mi], acc[mi][ni]);
            }
        }
        __syncthreads();
    }

    if (!vsec) {
        // Q,K: [B,H,T,HD].  D-row (g*4+r) <-> X-row m; D-col (c) <-> W-row n.
        #pragma unroll
        for (int mi = 0; mi < 4; ++mi)
            #pragma unroll
            for (int ni = 0; ni < 4; ++ni)
                #pragma unroll
                for (int r = 0; r < 4; ++r) {
                    const int m = m0 + wr + mi * 16 + g * 4 + r;
                    const int n = n0 + wc + ni * 16 + c;
                    const int b = m >> 11, t = m & (T_ - 1);
                    const int h = n >> 6,  hd = n & 63;
                    O[((size_t)((b << 4) + h) * T_ + t) * HD_ + hd] = f2bf(acc[mi][ni][r]);
                }
    } else {
        // V^T: [B,H,HD,T].  Swapped: D-row (g*4+r) <-> W-row n; D-col (c) <-> X-row m.
        #pragma unroll
        for (int mi = 0; mi < 4; ++mi)
            #pragma unroll
            for (int ni = 0; ni < 4; ++ni)
                #pragma unroll
                for (int r = 0; r < 4; ++r) {
                    const int n = n0 + wc + ni * 16 + g * 4 + r;
                    const int m = m0 + wr + mi * 16 + c;
                    const int b = m >> 11, t = m & (T_ - 1);
                    const int h = n >> 6,  hd = n & 63;
                    O[((size_t)((b << 4) + h) * HD_ + hd) * T_ + t] = f2bf(acc[mi][ni][r]);
                }
    }
}

// ---------------------------------------------------------------------------
// Causal flash attention v3: no LDS, no barriers, register double-buffered.
//  - grid (32, 64): x = 64-row q-tile, y = bh (consecutive blocks share K/V).
//  - Swapped QK^T: s = mfma(K,Q); softmax per-lane + 2 xor-shuffles.
//  - V^T stored [B,H,HD,T]: PV A-frags are 4 contiguous b128 loads.
//  - K/V frags for tile t+1 issued before computing tile t (ping-pong regs).
//  - Swapped PV: oacc = mfma(V^T, P): per-lane rescale and 1/l, no shuffles.
// ---------------------------------------------------------------------------
__global__ __launch_bounds__(256, 4)
void attn_kernel(const unsigned short* __restrict__ Q,
                 const unsigned short* __restrict__ K,
                 const unsigned short* __restrict__ VT,
                 unsigned short* __restrict__ Y)
{
    const int qt = blockIdx.x * 64;
    const int bh = blockIdx.y;          // 0..63
    const unsigned short* Qp  = Q  + (size_t)bh * T_ * HD_;
    const unsigned short* Kp  = K  + (size_t)bh * T_ * HD_;
    const unsigned short* VTp = VT + (size_t)bh * HD_ * T_;
    const int b = bh >> 4, h = bh & 15;

    const int lane = threadIdx.x & 63;
    const int w    = threadIdx.x >> 6;
    const int g    = lane >> 4;
    const int c    = lane & 15;
    const float SC = 0.18033688011112042f;   // (1/sqrt(64)) * log2(e)

    const int qw = qt + w * 16;

    // Q as B-operand frags, pre-scaled (softmax scale folded, log2 domain)
    bf16x8 qf[2];
    #pragma unroll
    for (int dk = 0; dk < 2; ++dk) {
        bf16x8 t = *(const bf16x8*)(Qp + (size_t)(qw + c) * HD_ + dk * 32 + g * 8);
        #pragma unroll
        for (int j = 0; j < 8; ++j)
            t[j] = (short)f2bf(bf2f((unsigned short)t[j]) * SC);
        qf[dk] = t;
    }

    float m_l = -1e30f, l_l = 0.f;
    f32x4 oacc[4] = {};
    const int nfull = qw >> 5;          // tile nfull is the masked/diagonal one

    auto loadK = [&](int tb, bf16x8 (&kf)[4]) {
        #pragma unroll
        for (int ni = 0; ni < 2; ++ni)
            #pragma unroll
            for (int dk = 0; dk < 2; ++dk)
                kf[ni * 2 + dk] = *(const bf16x8*)(Kp + (size_t)(tb + ni * 16 + c) * HD_ + dk * 32 + g * 8);
    };
    auto loadV = [&](int tb, bf16x8 (&vf)[4]) {
        #pragma unroll
        for (int dn = 0; dn < 4; ++dn)
            vf[dn] = *(const bf16x8*)(VTp + (size_t)(dn * 16 + c) * T_ + tb + g * 8);
    };

    auto tile = [&](int tb, bool masked, bf16x8 (&kf)[4], bf16x8 (&vf)[4]) {
        // S^T = K Q^T : lane holds S[tb + ni*16 + g*4 + r][qw + c]
        f32x4 s[2] = {};
        #pragma unroll
        for (int ni = 0; ni < 2; ++ni)
            #pragma unroll
            for (int dk = 0; dk < 2; ++dk)
                s[ni] = mfma16(kf[ni * 2 + dk], qf[dk], s[ni]);

        float p[2][4];
        #pragma unroll
        for (int ni = 0; ni < 2; ++ni)
            #pragma unroll
            for (int r = 0; r < 4; ++r)
                p[ni][r] = s[ni][r];
        if (masked) {
            #pragma unroll
            for (int ni = 0; ni < 2; ++ni)
                #pragma unroll
                for (int r = 0; r < 4; ++r)
                    p[ni][r] = (tb + ni * 16 + g * 4 + r <= qw + c) ? p[ni][r] : -1e30f;
        }

        float pmax = p[0][0];
        #pragma unroll
        for (int ni = 0; ni < 2; ++ni)
            #pragma unroll
            for (int r = 0; r < 4; ++r)
                pmax = fmaxf(pmax, p[ni][r]);
        pmax = fmaxf(pmax, __shfl_xor(pmax, 16));
        pmax = fmaxf(pmax, __shfl_xor(pmax, 32));

        const float mn = fmaxf(m_l, pmax);
        const float al = exp2_fast(m_l - mn);
        m_l = mn;

        float rs = 0.f;
        #pragma unroll
        for (int ni = 0; ni < 2; ++ni)
            #pragma unroll
            for (int r = 0; r < 4; ++r) {
                const float e = exp2_fast(p[ni][r] - mn);
                p[ni][r] = e;
                rs += e;
            }
        rs += __shfl_xor(rs, 16);
        rs += __shfl_xor(rs, 32);
        l_l = l_l * al + rs;

        // pack P pairs: P32[ni][hp] holds k-local = ni*16 + g*4 + 2hp, +1
        unsigned int P32[2][2];
        #pragma unroll
        for (int ni = 0; ni < 2; ++ni)
            #pragma unroll
            for (int hp = 0; hp < 2; ++hp)
                P32[ni][hp] = (unsigned int)f2bf(p[ni][2 * hp])
                            | ((unsigned int)f2bf(p[ni][2 * hp + 1]) << 16);

        // transpose: target lane (c,g) needs k = g*8 + j from lanes
        // sl0 = c + 32*(g&1) (j 0..3) and sl1 = sl0+16 (j 4..7), ni = g>>1
        const int sl0 = c + ((lane & 16) << 1);   // (g&1)<<5
        const int sl1 = sl0 + 16;
        const int q00 = __shfl((int)P32[0][0], sl0), q10 = __shfl((int)P32[1][0], sl0);
        const int q01 = __shfl((int)P32[0][1], sl0), q11 = __shfl((int)P32[1][1], sl0);
        const int q02 = __shfl((int)P32[0][0], sl1), q12 = __shfl((int)P32[1][0], sl1);
        const int q03 = __shfl((int)P32[0][1], sl1), q13 = __shfl((int)P32[1][1], sl1);
        const bool nhi = (g & 2) != 0;
        union { unsigned int u[4]; bf16x8 v; } pf;
        pf.u[0] = nhi ? q10 : q00;
        pf.u[1] = nhi ? q11 : q01;
        pf.u[2] = nhi ? q12 : q02;
        pf.u[3] = nhi ? q13 : q03;

        // rescale + PV (swapped): oacc rows = d, col = q = c (per-lane al)
        #pragma unroll
        for (int dn = 0; dn < 4; ++dn) {
            #pragma unroll
            for (int r = 0; r < 4; ++r)
                oacc[dn][r] *= al;
            oacc[dn] = mfma16(vf[dn], pf.v, oacc[dn]);
        }
    };

    // Register ping-pong pipeline (static indexing only).
    bf16x8 k0f[4], v0f[4], k1f[4], v1f[4];
    loadK(0, k0f); loadV(0, v0f);
    int kt = 0;
    while (true) {
        if (kt < nfull) { loadK((kt + 1) << 5, k1f); loadV((kt + 1) << 5, v1f); }
        tile(kt << 5, kt == nfull, k0f, v0f);
        if (kt == nfull) break;
        ++kt;
        if (kt < nfull) { loadK((kt + 1) << 5, k0f); loadV((kt + 1) << 5, v0f); }
        tile(kt << 5, kt == nfull, k1f, v1f);
        if (kt == nfull) break;
        ++kt;
    }

    // Epilogue: O[q = qw+c][d = dn*16 + g*4 + r], packed 8B stores
    const float li = 1.f / l_l;
    const size_t rowoff = (size_t)(b * T_ + qw + c) * D_ + h * 64;
    #pragma unroll
    for (int dn = 0; dn < 4; ++dn) {
        const unsigned int u0 = (unsigned int)f2bf(oacc[dn][0] * li)
                              | ((unsigned int)f2bf(oacc[dn][1] * li) << 16);
        const unsigned int u1 = (unsigned int)f2bf(oacc[dn][2] * li)
                              | ((unsigned int)f2bf(oacc[dn][3] * li) << 16);
        uint2 st; st.x = u0; st.y = u1;
        *(uint2*)(Y + rowoff + dn * 16 + g * 4) = st;
    }
}

// ---------------------------------------------------------------------------
// Output projection:  out = Y @ Wp^T + bp.  Y bf16[8192,1024]; out fp32.
// ---------------------------------------------------------------------------
__global__ __launch_bounds__(256, 2)
void proj_kernel(const unsigned short* __restrict__ Yin,
                 const unsigned short* __restrict__ Wp,
                 const float* __restrict__ bp,
                 float* __restrict__ Out)
{
    __shared__ unsigned short As[128 * 64];
    __shared__ unsigned short Bs[128 * 64];

    const int m0 = blockIdx.x * 128;
    const int n0 = blockIdx.y * 128;
    const int tid  = threadIdx.x;
    const int lane = tid & 63;
    const int wv   = tid >> 6;
    const int wr   = (wv >> 1) * 64;
    const int wc   = (wv & 1) * 64;
    const int g    = lane >> 4;
    const int c    = lane & 15;

    f32x4 acc[4][4] = {};

    for (int k0 = 0; k0 < D_; k0 += 64) {
        #pragma unroll
        for (int i = 0; i < 4; ++i) {
            const int flat = i * 2048 + tid * 8;
            const int row = flat >> 6, col = flat & 63;
            gl_lds16(Yin + (size_t)(m0 + row) * D_ + k0 + col, As + flat);
            gl_lds16(Wp  + (size_t)(n0 + row) * D_ + k0 + col, Bs + flat);
        }
        __syncthreads();
        #pragma unroll
        for (int kk = 0; kk < 64; kk += 32) {
            bf16x8 af[4], bg[4];
            #pragma unroll
            for (int mi = 0; mi < 4; ++mi)
                af[mi] = *(const bf16x8*)(As + (wr + mi * 16 + c) * 64 + kk + g * 8);
            #pragma unroll
            for (int ni = 0; ni < 4; ++ni)
                bg[ni] = *(const bf16x8*)(Bs + (wc + ni * 16 + c) * 64 + kk + g * 8);
            #pragma unroll
            for (int mi = 0; mi < 4; ++mi)
                #pragma unroll
                for (int ni = 0; ni < 4; ++ni)
                    acc[mi][ni] = mfma16(af[mi], bg[ni], acc[mi][ni]);
        }
        __syncthreads();
    }

    #pragma unroll
    for (int mi = 0; mi < 4; ++mi) {
        #pragma unroll
        for (int ni = 0; ni < 4; ++ni) {
            const int n = n0 + wc + ni * 16 + c;
            const float bb = bp[n];
            #pragma unroll
            for (int r = 0; r < 4; ++r) {
                const int m = m0 + wr + mi * 16 + g * 4 + r;
                Out[(size_t)m * D_ + n] = acc[mi][ni][r] + bb;
            }
        }
    }
}

// ---------------------------------------------------------------------------
extern "C" void kernel_launch(void* const* d_in, const int* in_sizes, int n_in,
                              void* d_out, int out_size, void* d_ws, size_t ws_size,
                              hipStream_t stream) {
    const float* x  = (const float*)d_in[0];
    const float* Wq = (const float*)d_in[1];
    const float* Wk = (const float*)d_in[2];
    const float* Wv = (const float*)d_in[3];
    const float* Wp = (const float*)d_in[4];
    const float* bp = (const float*)d_in[5];
    float* out = (float*)d_out;

    const size_t SZ  = (size_t)M_ * D_;      // 8388608
    const size_t WSZ = (size_t)D_ * D_;      // 1048576
    unsigned short* ws = (unsigned short*)d_ws;
    unsigned short* XB  = ws;                 // also Y after qkv
    unsigned short* WQB = XB  + SZ;
    unsigned short* WKB = WQB + WSZ;
    unsigned short* WVB = WKB + WSZ;
    unsigned short* WPB = WVB + WSZ;
    unsigned short* Qw  = WPB + WSZ;
    unsigned short* Kw  = Qw + SZ;
    unsigned short* Vw  = Kw + SZ;            // V^T [B,H,HD,T]
    unsigned short* Yw  = XB;                 // overlay: x_bf16 dead after qkv

    dim3 blk(256);
    cvt_kernel<<<dim3(SZ / 1024),  blk, 0, stream>>>(x,  XB);
    cvt_kernel<<<dim3(WSZ / 1024), blk, 0, stream>>>(Wq, WQB);
    cvt_kernel<<<dim3(WSZ / 1024), blk, 0, stream>>>(Wk, WKB);
    cvt_kernel<<<dim3(WSZ / 1024), blk, 0, stream>>>(Wv, WVB);
    cvt_kernel<<<dim3(WSZ / 1024), blk, 0, stream>>>(Wp, WPB);

    qkv_kernel <<<dim3(M_ / 128, 24), blk, 0, stream>>>(XB, WQB, WKB, WVB, Qw, Kw, Vw);
    attn_kernel<<<dim3(T_ / 64, B_ * H_), blk, 0, stream>>>(Qw, Kw, Vw, Yw);
    proj_kernel<<<dim3(M_ / 128, D_ / 128), blk, 0, stream>>>(Yw, WPB, bp, out);
}

// Round 6
// 360.343 us; speedup vs baseline: 1.5640x; 1.5640x over previous
//
#include <hip/hip_runtime.h>
#include <hip/hip_bf16.h>
#include <math.h>

// Problem: CausalSelfAttention  B=4 T=2048 D=1024 H=16 HD=64
// d_in: fp32 x[4,2048,1024], Wq,Wk,Wv,Wp[1024,1024], bp[1024]; d_out: fp32 y.
// Pipeline: cvt(fp32->bf16 into ws) -> qkv -> attn -> proj.
// V stored TRANSPOSED [B,H,HD,T] (operand-swapped MFMA in qkv) so attention's
// PV A-operand fragments are contiguous b128 loads.
// attn grid: blockIdx.x = bh (fast axis) -> XCD k sees only bh%8==k panels
// (8 x 512KB = 4MB = one XCD L2); blockIdx.y = pr with causal pairing
// (q-tiles pr and 31-pr) -> uniform work per block.

#define B_  4
#define T_  2048
#define D_  1024
#define H_  16
#define HD_ 64
#define M_  (B_ * T_)   // 8192 rows

typedef short bf16x8 __attribute__((ext_vector_type(8)));
typedef float f32x4  __attribute__((ext_vector_type(4)));

__device__ __forceinline__ f32x4 mfma16(bf16x8 a, bf16x8 b, f32x4 c) {
    return __builtin_amdgcn_mfma_f32_16x16x32_bf16(a, b, c, 0, 0, 0);
}

__device__ __forceinline__ void gl_lds16(const unsigned short* g, unsigned short* l) {
    __builtin_amdgcn_global_load_lds(
        (const __attribute__((address_space(1))) void*)g,
        (__attribute__((address_space(3))) void*)l, 16, 0, 0);
}

__device__ __forceinline__ unsigned short f2bf(float f) {
    union { __hip_bfloat16 h; unsigned short u; } cv;
    cv.h = __float2bfloat16(f);
    return cv.u;
}
__device__ __forceinline__ float bf2f(unsigned short u) {
    return __uint_as_float(((unsigned)u) << 16);
}
__device__ __forceinline__ float exp2_fast(float x) {
    return __builtin_amdgcn_exp2f(x);   // v_exp_f32: 2^x
}

struct su4 { unsigned short x, y, z, w; };

// ---------------------------------------------------------------------------
__global__ __launch_bounds__(256)
void cvt_kernel(const float* __restrict__ in, unsigned short* __restrict__ out) {
    const int i = blockIdx.x * 256 + threadIdx.x;
    const float4 v = ((const float4*)in)[i];
    su4 o;
    o.x = f2bf(v.x); o.y = f2bf(v.y); o.z = f2bf(v.z); o.w = f2bf(v.w);
    ((su4*)out)[i] = o;
}

// ---------------------------------------------------------------------------
// Fused QKV GEMM: C = X @ W^T.  Q,K scattered to [B,H,T,HD]; V to [B,H,HD,T]
// via operand-swapped MFMA (acc holds C^T for the V section).
// ---------------------------------------------------------------------------
__global__ __launch_bounds__(256, 2)
void qkv_kernel(const unsigned short* __restrict__ X,
                const unsigned short* __restrict__ Wq,
                const unsigned short* __restrict__ Wk,
                const unsigned short* __restrict__ Wv,
                unsigned short* __restrict__ Qo,
                unsigned short* __restrict__ Ko,
                unsigned short* __restrict__ Vo)
{
    __shared__ unsigned short As[128 * 64];
    __shared__ unsigned short Bs[128 * 64];

    const int m0 = blockIdx.x * 128;
    const int by = blockIdx.y;
    const unsigned short* W = (by < 8) ? Wq : (by < 16) ? Wk : Wv;
    unsigned short*       O = (by < 8) ? Qo : (by < 16) ? Ko : Vo;
    const int n0   = (by & 7) * 128;
    const bool vsec = (by >= 16);
    const int tid  = threadIdx.x;
    const int lane = tid & 63;
    const int wv   = tid >> 6;
    const int wr   = (wv >> 1) * 64;
    const int wc   = (wv & 1) * 64;
    const int g    = lane >> 4;
    const int c    = lane & 15;

    f32x4 acc[4][4] = {};

    for (int k0 = 0; k0 < D_; k0 += 64) {
        #pragma unroll
        for (int i = 0; i < 4; ++i) {
            const int flat = i * 2048 + tid * 8;
            const int row = flat >> 6, col = flat & 63;
            gl_lds16(X + (size_t)(m0 + row) * D_ + k0 + col, As + flat);
            gl_lds16(W + (size_t)(n0 + row) * D_ + k0 + col, Bs + flat);
        }
        __syncthreads();
        #pragma unroll
        for (int kk = 0; kk < 64; kk += 32) {
            bf16x8 af[4], bg[4];
            #pragma unroll
            for (int mi = 0; mi < 4; ++mi)
                af[mi] = *(const bf16x8*)(As + (wr + mi * 16 + c) * 64 + kk + g * 8);
            #pragma unroll
            for (int ni = 0; ni < 4; ++ni)
                bg[ni] = *(const bf16x8*)(Bs + (wc + ni * 16 + c) * 64 + kk + g * 8);
            if (!vsec) {
                #pragma unroll
                for (int mi = 0; mi < 4; ++mi)
                    #pragma unroll
                    for (int ni = 0; ni < 4; ++ni)
                        acc[mi][ni] = mfma16(af[mi], bg[ni], acc[mi][ni]);
            } else {
                #pragma unroll
                for (int mi = 0; mi < 4; ++mi)
                    #pragma unroll
                    for (int ni = 0; ni < 4; ++ni)
                        acc[mi][ni] = mfma16(bg[ni], af[mi], acc[mi][ni]);
            }
        }
        __syncthreads();
    }

    if (!vsec) {
        // Q,K: [B,H,T,HD].  D-row (g*4+r) <-> X-row m; D-col (c) <-> W-row n.
        #pragma unroll
        for (int mi = 0; mi < 4; ++mi)
            #pragma unroll
            for (int ni = 0; ni < 4; ++ni)
                #pragma unroll
                for (int r = 0; r < 4; ++r) {
                    const int m = m0 + wr + mi * 16 + g * 4 + r;
                    const int n = n0 + wc + ni * 16 + c;
                    const int b = m >> 11, t = m & (T_ - 1);
                    const int h = n >> 6,  hd = n & 63;
                    O[((size_t)((b << 4) + h) * T_ + t) * HD_ + hd] = f2bf(acc[mi][ni][r]);
                }
    } else {
        // V^T: [B,H,HD,T].  Swapped: D-row (g*4+r) <-> W-row n; D-col (c) <-> X-row m.
        #pragma unroll
        for (int mi = 0; mi < 4; ++mi)
            #pragma unroll
            for (int ni = 0; ni < 4; ++ni)
                #pragma unroll
                for (int r = 0; r < 4; ++r) {
                    const int n = n0 + wc + ni * 16 + g * 4 + r;
                    const int m = m0 + wr + mi * 16 + c;
                    const int b = m >> 11, t = m & (T_ - 1);
                    const int h = n >> 6,  hd = n & 63;
                    O[((size_t)((b << 4) + h) * HD_ + hd) * T_ + t] = f2bf(acc[mi][ni][r]);
                }
    }
}

// ---------------------------------------------------------------------------
// Causal flash attention v4: no LDS/barriers; register double-buffered K/V;
// round-4 grid (bh fast axis + causal pairing) for XCD-L2 panel residency.
// ---------------------------------------------------------------------------
__global__ __launch_bounds__(256, 4)
void attn_kernel(const unsigned short* __restrict__ Q,
                 const unsigned short* __restrict__ K,
                 const unsigned short* __restrict__ VT,
                 unsigned short* __restrict__ Y)
{
    const int bh = blockIdx.x;          // 0..63 (fast axis -> XCD partition)
    const int pr = blockIdx.y;          // 0..15
    const unsigned short* Qp  = Q  + (size_t)bh * T_ * HD_;
    const unsigned short* Kp  = K  + (size_t)bh * T_ * HD_;
    const unsigned short* VTp = VT + (size_t)bh * HD_ * T_;
    const int b = bh >> 4, h = bh & 15;

    const int lane = threadIdx.x & 63;
    const int w    = threadIdx.x >> 6;
    const int g    = lane >> 4;
    const int c    = lane & 15;
    const float SC = 0.18033688011112042f;   // (1/sqrt(64)) * log2(e)

    for (int hf = 0; hf < 2; ++hf) {
        const int qt = (hf ? 31 - pr : pr) * 64;
        const int qw = qt + w * 16;

        // Q as B-operand frags, pre-scaled (softmax scale folded, log2 domain)
        bf16x8 qf[2];
        #pragma unroll
        for (int dk = 0; dk < 2; ++dk) {
            bf16x8 t = *(const bf16x8*)(Qp + (size_t)(qw + c) * HD_ + dk * 32 + g * 8);
            #pragma unroll
            for (int j = 0; j < 8; ++j)
                t[j] = (short)f2bf(bf2f((unsigned short)t[j]) * SC);
            qf[dk] = t;
        }

        float m_l = -1e30f, l_l = 0.f;
        f32x4 oacc[4] = {};
        const int nfull = qw >> 5;      // tile nfull is the masked/diagonal one

        auto loadK = [&](int tb, bf16x8 (&kf)[4]) {
            #pragma unroll
            for (int ni = 0; ni < 2; ++ni)
                #pragma unroll
                for (int dk = 0; dk < 2; ++dk)
                    kf[ni * 2 + dk] = *(const bf16x8*)(Kp + (size_t)(tb + ni * 16 + c) * HD_ + dk * 32 + g * 8);
        };
        auto loadV = [&](int tb, bf16x8 (&vf)[4]) {
            #pragma unroll
            for (int dn = 0; dn < 4; ++dn)
                vf[dn] = *(const bf16x8*)(VTp + (size_t)(dn * 16 + c) * T_ + tb + g * 8);
        };

        auto tile = [&](int tb, bool masked, bf16x8 (&kf)[4], bf16x8 (&vf)[4]) {
            // S^T = K Q^T : lane holds S[tb + ni*16 + g*4 + r][qw + c]
            f32x4 s[2] = {};
            #pragma unroll
            for (int ni = 0; ni < 2; ++ni)
                #pragma unroll
                for (int dk = 0; dk < 2; ++dk)
                    s[ni] = mfma16(kf[ni * 2 + dk], qf[dk], s[ni]);

            float p[2][4];
            #pragma unroll
            for (int ni = 0; ni < 2; ++ni)
                #pragma unroll
                for (int r = 0; r < 4; ++r)
                    p[ni][r] = s[ni][r];
            if (masked) {
                #pragma unroll
                for (int ni = 0; ni < 2; ++ni)
                    #pragma unroll
                    for (int r = 0; r < 4; ++r)
                        p[ni][r] = (tb + ni * 16 + g * 4 + r <= qw + c) ? p[ni][r] : -1e30f;
            }

            float pmax = p[0][0];
            #pragma unroll
            for (int ni = 0; ni < 2; ++ni)
                #pragma unroll
                for (int r = 0; r < 4; ++r)
                    pmax = fmaxf(pmax, p[ni][r]);
            pmax = fmaxf(pmax, __shfl_xor(pmax, 16));
            pmax = fmaxf(pmax, __shfl_xor(pmax, 32));

            const float mn = fmaxf(m_l, pmax);
            const float al = exp2_fast(m_l - mn);
            m_l = mn;

            float rs = 0.f;
            #pragma unroll
            for (int ni = 0; ni < 2; ++ni)
                #pragma unroll
                for (int r = 0; r < 4; ++r) {
                    const float e = exp2_fast(p[ni][r] - mn);
                    p[ni][r] = e;
                    rs += e;
                }
            rs += __shfl_xor(rs, 16);
            rs += __shfl_xor(rs, 32);
            l_l = l_l * al + rs;

            // pack P pairs: P32[ni][hp] holds k-local = ni*16 + g*4 + 2hp, +1
            unsigned int P32[2][2];
            #pragma unroll
            for (int ni = 0; ni < 2; ++ni)
                #pragma unroll
                for (int hp = 0; hp < 2; ++hp)
                    P32[ni][hp] = (unsigned int)f2bf(p[ni][2 * hp])
                                | ((unsigned int)f2bf(p[ni][2 * hp + 1]) << 16);

            // transpose: target lane (c,g) needs k = g*8 + j from lanes
            // sl0 = c + 32*(g&1) (j 0..3) and sl1 = sl0+16 (j 4..7), ni = g>>1
            const int sl0 = c + ((lane & 16) << 1);   // (g&1)<<5
            const int sl1 = sl0 + 16;
            const int q00 = __shfl((int)P32[0][0], sl0), q10 = __shfl((int)P32[1][0], sl0);
            const int q01 = __shfl((int)P32[0][1], sl0), q11 = __shfl((int)P32[1][1], sl0);
            const int q02 = __shfl((int)P32[0][0], sl1), q12 = __shfl((int)P32[1][0], sl1);
            const int q03 = __shfl((int)P32[0][1], sl1), q13 = __shfl((int)P32[1][1], sl1);
            const bool nhi = (g & 2) != 0;
            union { unsigned int u[4]; bf16x8 v; } pf;
            pf.u[0] = nhi ? q10 : q00;
            pf.u[1] = nhi ? q11 : q01;
            pf.u[2] = nhi ? q12 : q02;
            pf.u[3] = nhi ? q13 : q03;

            // rescale + PV (swapped): oacc rows = d, col = q = c (per-lane al)
            #pragma unroll
            for (int dn = 0; dn < 4; ++dn) {
                #pragma unroll
                for (int r = 0; r < 4; ++r)
                    oacc[dn][r] *= al;
                oacc[dn] = mfma16(vf[dn], pf.v, oacc[dn]);
            }
        };

        // Register ping-pong pipeline (static indexing only).
        bf16x8 k0f[4], v0f[4], k1f[4], v1f[4];
        loadK(0, k0f); loadV(0, v0f);
        int kt = 0;
        while (true) {
            if (kt < nfull) { loadK((kt + 1) << 5, k1f); loadV((kt + 1) << 5, v1f); }
            tile(kt << 5, kt == nfull, k0f, v0f);
            if (kt == nfull) break;
            ++kt;
            if (kt < nfull) { loadK((kt + 1) << 5, k0f); loadV((kt + 1) << 5, v0f); }
            tile(kt << 5, kt == nfull, k1f, v1f);
            if (kt == nfull) break;
            ++kt;
        }

        // Epilogue: O[q = qw+c][d = dn*16 + g*4 + r], packed 8B stores
        const float li = 1.f / l_l;
        const size_t rowoff = (size_t)(b * T_ + qw + c) * D_ + h * 64;
        #pragma unroll
        for (int dn = 0; dn < 4; ++dn) {
            const unsigned int u0 = (unsigned int)f2bf(oacc[dn][0] * li)
                                  | ((unsigned int)f2bf(oacc[dn][1] * li) << 16);
            const unsigned int u1 = (unsigned int)f2bf(oacc[dn][2] * li)
                                  | ((unsigned int)f2bf(oacc[dn][3] * li) << 16);
            uint2 st; st.x = u0; st.y = u1;
            *(uint2*)(Y + rowoff + dn * 16 + g * 4) = st;
        }
    }
}

// ---------------------------------------------------------------------------
// Output projection:  out = Y @ Wp^T + bp.  Y bf16[8192,1024]; out fp32.
// ---------------------------------------------------------------------------
__global__ __launch_bounds__(256, 2)
void proj_kernel(const unsigned short* __restrict__ Yin,
                 const unsigned short* __restrict__ Wp,
                 const float* __restrict__ bp,
                 float* __restrict__ Out)
{
    __shared__ unsigned short As[128 * 64];
    __shared__ unsigned short Bs[128 * 64];

    const int m0 = blockIdx.x * 128;
    const int n0 = blockIdx.y * 128;
    const int tid  = threadIdx.x;
    const int lane = tid & 63;
    const int wv   = tid >> 6;
    const int wr   = (wv >> 1) * 64;
    const int wc   = (wv & 1) * 64;
    const int g    = lane >> 4;
    const int c    = lane & 15;

    f32x4 acc[4][4] = {};

    for (int k0 = 0; k0 < D_; k0 += 64) {
        #pragma unroll
        for (int i = 0; i < 4; ++i) {
            const int flat = i * 2048 + tid * 8;
            const int row = flat >> 6, col = flat & 63;
            gl_lds16(Yin + (size_t)(m0 + row) * D_ + k0 + col, As + flat);
            gl_lds16(Wp  + (size_t)(n0 + row) * D_ + k0 + col, Bs + flat);
        }
        __syncthreads();
        #pragma unroll
        for (int kk = 0; kk < 64; kk += 32) {
            bf16x8 af[4], bg[4];
            #pragma unroll
            for (int mi = 0; mi < 4; ++mi)
                af[mi] = *(const bf16x8*)(As + (wr + mi * 16 + c) * 64 + kk + g * 8);
            #pragma unroll
            for (int ni = 0; ni < 4; ++ni)
                bg[ni] = *(const bf16x8*)(Bs + (wc + ni * 16 + c) * 64 + kk + g * 8);
            #pragma unroll
            for (int mi = 0; mi < 4; ++mi)
                #pragma unroll
                for (int ni = 0; ni < 4; ++ni)
                    acc[mi][ni] = mfma16(af[mi], bg[ni], acc[mi][ni]);
        }
        __syncthreads();
    }

    #pragma unroll
    for (int mi = 0; mi < 4; ++mi) {
        #pragma unroll
        for (int ni = 0; ni < 4; ++ni) {
            const int n = n0 + wc + ni * 16 + c;
            const float bb = bp[n];
            #pragma unroll
            for (int r = 0; r < 4; ++r) {
                const int m = m0 + wr + mi * 16 + g * 4 + r;
                Out[(size_t)m * D_ + n] = acc[mi][ni][r] + bb;
            }
        }
    }
}

// ---------------------------------------------------------------------------
extern "C" void kernel_launch(void* const* d_in, const int* in_sizes, int n_in,
                              void* d_out, int out_size, void* d_ws, size_t ws_size,
                              hipStream_t stream) {
    const float* x  = (const float*)d_in[0];
    const float* Wq = (const float*)d_in[1];
    const float* Wk = (const float*)d_in[2];
    const float* Wv = (const float*)d_in[3];
    const float* Wp = (const float*)d_in[4];
    const float* bp = (const float*)d_in[5];
    float* out = (float*)d_out;

    const size_t SZ  = (size_t)M_ * D_;      // 8388608
    const size_t WSZ = (size_t)D_ * D_;      // 1048576
    unsigned short* ws = (unsigned short*)d_ws;
    unsigned short* XB  = ws;                 // also Y after qkv
    unsigned short* WQB = XB  + SZ;
    unsigned short* WKB = WQB + WSZ;
    unsigned short* WVB = WKB + WSZ;
    unsigned short* WPB = WVB + WSZ;
    unsigned short* Qw  = WPB + WSZ;
    unsigned short* Kw  = Qw + SZ;
    unsigned short* Vw  = Kw + SZ;            // V^T [B,H,HD,T]
    unsigned short* Yw  = XB;                 // overlay: x_bf16 dead after qkv

    dim3 blk(256);
    cvt_kernel<<<dim3(SZ / 1024),  blk, 0, stream>>>(x,  XB);
    cvt_kernel<<<dim3(WSZ / 1024), blk, 0, stream>>>(Wq, WQB);
    cvt_kernel<<<dim3(WSZ / 1024), blk, 0, stream>>>(Wk, WKB);
    cvt_kernel<<<dim3(WSZ / 1024), blk, 0, stream>>>(Wv, WVB);
    cvt_kernel<<<dim3(WSZ / 1024), blk, 0, stream>>>(Wp, WPB);

    qkv_kernel <<<dim3(M_ / 128, 24), blk, 0, stream>>>(XB, WQB, WKB, WVB, Qw, Kw, Vw);
    attn_kernel<<<dim3(B_ * H_, 16), blk, 0, stream>>>(Qw, Kw, Vw, Yw);
    proj_kernel<<<dim3(M_ / 128, D_ / 128), blk, 0, stream>>>(Yw, WPB, bp, out);
}